// Round 10
// baseline (348.375 us; speedup 1.0000x reference)
//
#include <hip/hip_runtime.h>
#include <math.h>

#define NN 50000
#define EE 800000
#define DIN 300
#define DH 128
#define NG 128
#define RSIZE 6250  // NN/8 dst-range per XCD partition

typedef __attribute__((ext_vector_type(8))) short short8;
typedef __attribute__((ext_vector_type(4))) float floatx4;

__device__ __forceinline__ float gelu_exact(float x) {
  return 0.5f * x * (1.0f + erff(x * 0.7071067811865476f));
}

__device__ __forceinline__ void split_bf16(float v, unsigned short& hi, unsigned short& lo) {
  unsigned int u = __float_as_uint(v);
  hi = (unsigned short)(u >> 16);
  float fh = __uint_as_float((unsigned int)hi << 16);
  lo = (unsigned short)(__float_as_uint(v - fh) >> 16);
}

__device__ __forceinline__ unsigned short f2bf_rne(float x) {
  unsigned int u = __float_as_uint(x);
  unsigned int r = (u + 0x7FFFu + ((u >> 16) & 1u)) >> 16;
  return (unsigned short)r;
}

__device__ __forceinline__ float bf_lo(unsigned u) { return __uint_as_float(u << 16); }
__device__ __forceinline__ float bf_hi(unsigned u) { return __uint_as_float(u & 0xFFFF0000u); }

// async 16B global->LDS DMA (gfx950). LDS dest = wave-uniform base + lane*16.
__device__ __forceinline__ void async_ld16(void* lds, const void* g) {
  __builtin_amdgcn_global_load_lds(
      (const __attribute__((address_space(1))) unsigned int*)(unsigned long long)g,
      (__attribute__((address_space(3))) unsigned int*)(unsigned int)(unsigned long long)lds,
      16, 0, 0);
}

// ---------------- CSR build (XCD-partitioned by dst range) ----------------

__global__ __launch_bounds__(256) void count_part_kernel(const int* __restrict__ ei,
                                                         int* __restrict__ deg,
                                                         int blocksPerRange) {
  const int r = blockIdx.x & 7;
  const int t = blockIdx.x >> 3;
  const int lo = r * RSIZE, hi = lo + RSIZE;
  const int total = EE + NN;
  const int step = blocksPerRange * 256;
  for (int e0 = t * 256; e0 < total; e0 += step) {
    int e = e0 + threadIdx.x;
    if (e < total) {
      int d = (e < EE) ? ei[EE + e] : (e - EE);
      if (d >= lo && d < hi) atomicAdd(&deg[d], 1);
    }
  }
}

__global__ __launch_bounds__(1024) void scan_part_kernel(const int* __restrict__ deg,
                                                         int* __restrict__ rowptr,
                                                         int* __restrict__ bsum) {
  __shared__ int wsum[16];
  const int tid = threadIdx.x;
  const int lane = tid & 63;
  const int wid = tid >> 6;
  int idx = blockIdx.x * 1024 + tid;
  int v = (idx < NN) ? deg[idx] : 0;
  int x = v;
#pragma unroll
  for (int d = 1; d < 64; d <<= 1) {
    int y = __shfl_up(x, d, 64);
    if (lane >= d) x += y;
  }
  if (lane == 63) wsum[wid] = x;
  __syncthreads();
  if (wid == 0) {
    int s = (lane < 16) ? wsum[lane] : 0;
#pragma unroll
    for (int d = 1; d < 16; d <<= 1) {
      int y = __shfl_up(s, d, 64);
      if (lane >= d) s += y;
    }
    if (lane < 16) wsum[lane] = s;
  }
  __syncthreads();
  int woff = (wid > 0) ? wsum[wid - 1] : 0;
  int incl = x + woff;
  if (idx < NN) rowptr[idx] = incl - v;
  if (tid == 1023) bsum[blockIdx.x] = incl;
}

__global__ __launch_bounds__(64) void scan_sums_kernel(const int* __restrict__ bsum,
                                                       int* __restrict__ boff, int nb) {
  int lane = threadIdx.x;
  int v = (lane < nb) ? bsum[lane] : 0;
  int x = v;
#pragma unroll
  for (int d = 1; d < 64; d <<= 1) {
    int y = __shfl_up(x, d, 64);
    if (lane >= d) x += y;
  }
  if (lane < nb) boff[lane] = x - v;
  if (lane == nb - 1) boff[nb] = x;
}

__global__ __launch_bounds__(256) void scan_add_kernel(int* __restrict__ rowptr,
                                                       const int* __restrict__ boff,
                                                       int* __restrict__ cursor, int nb) {
  int i = blockIdx.x * 256 + threadIdx.x;
  if (i < NN) {
    int r = rowptr[i] + boff[i >> 10];
    rowptr[i] = r;
    cursor[i] = r;
  } else if (i == NN) {
    rowptr[NN] = boff[nb];
  }
}

__global__ __launch_bounds__(256) void scatter_part_kernel(const int* __restrict__ ei,
                                                           int* __restrict__ cursor,
                                                           int* __restrict__ colA,
                                                           int blocksPerRange) {
  const int r = blockIdx.x & 7;
  const int t = blockIdx.x >> 3;
  const int lo = r * RSIZE, hi = lo + RSIZE;
  const int total = EE + NN;
  const int step = blocksPerRange * 256;
  for (int e0 = t * 256; e0 < total; e0 += step) {
    int e = e0 + threadIdx.x;
    if (e < total) {
      int d = (e < EE) ? ei[EE + e] : (e - EE);
      if (d >= lo && d < hi) {
        int s = (e < EE) ? ei[e] : d;
        int p = atomicAdd(&cursor[d], 1);
        colA[p] = s;
      }
    }
  }
}

// ---------------- B pre-transpose + split to bf16 hi/lo ----------------

__global__ __launch_bounds__(256) void convert_bt_kernel(const float* __restrict__ B,
                                                         unsigned short* __restrict__ Bth,
                                                         unsigned short* __restrict__ Btl,
                                                         int K, int Kpad) {
  int i = blockIdx.x * 256 + threadIdx.x;
  int n = i / Kpad, k = i % Kpad;
  if (n >= 128) return;
  float v = (k < K) ? B[(long)k * 128 + n] : 0.f;
  unsigned short h, l;
  split_bf16(v, h, l);
  Bth[(long)n * Kpad + k] = h;
  Btl[(long)n * Kpad + k] = l;
}

// ---------------- MFMA split-bf16 GEMM + fused attention row-dots ----------------
// C (bf16) [M,128] = A[M,K] @ B[K,128]; BM=32, BN=128, BK=32.
// Waves: wr=w&1 picks 16-row group, wc=w>>1 picks 64-col half; acc = 4 tiles.
// Grid doubled vs BM=64 (1563 blocks, ~5 resident/CU at 32KB LDS -> ~62% occ)
// for latency hiding. A frags global->reg, B via double-buffered DMA, one
// barrier/step. Row-dot halves combined through LDS (aliased over dead Bls).

__global__ __launch_bounds__(256) void gemm_mfma_kernel(
    const float* __restrict__ A,
    const unsigned short* __restrict__ Bth, const unsigned short* __restrict__ Btl,
    unsigned short* __restrict__ C, int M, int K, int Kpad,
    const float* __restrict__ avs, const float* __restrict__ avd,
    float* __restrict__ aS, float* __restrict__ aD) {
  __shared__ __align__(16) unsigned short Bls[2][2][128 * 32];  // [buf][plane][n*32+k]

  const int tid = threadIdx.x;
  const int lane = tid & 63;
  const int w = tid >> 6;
  const int wr = w & 1;       // row group (16 rows)
  const int wc = w >> 1;      // column half (64 cols)
  const int q = lane >> 4;
  const int m16 = lane & 15;
  const int row0 = blockIdx.x * 32;
  const int myrow = row0 + wr * 16 + m16;
  const bool rok = myrow < M;
  const long abase = (long)myrow * K;

  // DMA source geometry (two 16-row instrs per plane per wave; covers n 0..127)
  const int rl = lane >> 2, qq0 = lane & 3;
  const int nb0 = w * 16 + rl;
  const int nb1 = 64 + w * 16 + rl;
  const long boff0 = (long)nb0 * Kpad + (long)((qq0 ^ ((nb0 >> 1) & 3)) * 8);
  const long boff1 = (long)nb1 * Kpad + (long)((qq0 ^ ((nb1 >> 1) & 3)) * 8);

  floatx4 acc[4];
#pragma unroll
  for (int i = 0; i < 4; i++) acc[i] = (floatx4)(0.f);

  const int nsteps = Kpad / 32;

  float4 vA0, vA1, nA0, nA1;
  nA0 = nA1 = make_float4(0.f, 0.f, 0.f, 0.f);

  auto stageB = [&](int s, int nb) {
    const int k0 = s * 32;
    async_ld16(&Bls[nb][0][(w * 16) * 32], Bth + boff0 + k0);
    async_ld16(&Bls[nb][0][(64 + w * 16) * 32], Bth + boff1 + k0);
    async_ld16(&Bls[nb][1][(w * 16) * 32], Btl + boff0 + k0);
    async_ld16(&Bls[nb][1][(64 + w * 16) * 32], Btl + boff1 + k0);
  };
  auto loadA = [&](int s, float4& x0, float4& x1) {
    const int k0 = s * 32 + q * 8;
    x0 = make_float4(0.f, 0.f, 0.f, 0.f);
    x1 = x0;
    if (rok) {
      if (k0 + 4 <= K) x0 = *(const float4*)&A[abase + k0];
      if (k0 + 8 <= K) x1 = *(const float4*)&A[abase + k0 + 4];
    }
  };

  stageB(0, 0);
  loadA(0, vA0, vA1);
  __syncthreads();  // vmcnt drained before barrier -> DMA complete

  for (int s = 0; s < nsteps; s++) {
    const int cur = s & 1;
    if (s + 1 < nsteps) {
      stageB(s + 1, 1 ^ cur);   // async DMA, zero VGPR cost
      loadA(s + 1, nA0, nA1);   // stays in flight across the MFMAs
    }
    float av[8] = {vA0.x, vA0.y, vA0.z, vA0.w, vA1.x, vA1.y, vA1.z, vA1.w};
    union {
      unsigned u[4];
      short8 s8;
    } Uh, Ul;
#pragma unroll
    for (int i = 0; i < 4; i++) {
      unsigned short ha, la, hb, lb;
      split_bf16(av[2 * i], ha, la);
      split_bf16(av[2 * i + 1], hb, lb);
      Uh.u[i] = (unsigned)ha | ((unsigned)hb << 16);
      Ul.u[i] = (unsigned)la | ((unsigned)lb << 16);
    }
    short8 afh = Uh.s8, afl = Ul.s8;
#pragma unroll
    for (int ct = 0; ct < 4; ct++) {
      int n = wc * 64 + ct * 16 + m16;
      int qv = (q ^ ((n >> 1) & 3)) * 8;
      short8 bfh = *(const short8*)&Bls[cur][0][n * 32 + qv];
      short8 bfl = *(const short8*)&Bls[cur][1][n * 32 + qv];
      acc[ct] = __builtin_amdgcn_mfma_f32_16x16x32_bf16(afh, bfh, acc[ct], 0, 0, 0);
      acc[ct] = __builtin_amdgcn_mfma_f32_16x16x32_bf16(afh, bfl, acc[ct], 0, 0, 0);
      acc[ct] = __builtin_amdgcn_mfma_f32_16x16x32_bf16(afl, bfh, acc[ct], 0, 0, 0);
    }
    vA0 = nA0;
    vA1 = nA1;
    __syncthreads();  // single barrier: drains next-step DMA (issued pre-compute)
  }

  // ---- epilogue: C store + row-dots (partial per col-half, combined via LDS)
  float avs_r[4], avd_r[4];
#pragma unroll
  for (int ct = 0; ct < 4; ct++) {
    avs_r[ct] = avs[wc * 64 + ct * 16 + m16];
    avd_r[ct] = avd[wc * 64 + ct * 16 + m16];
  }
  float psA[4], pdA[4];
#pragma unroll
  for (int reg = 0; reg < 4; reg++) {
    int grow = row0 + wr * 16 + q * 4 + reg;
    bool ok = grow < M;
    float ps = 0.f, pd = 0.f;
#pragma unroll
    for (int ct = 0; ct < 4; ct++) {
      float c = acc[ct][reg];
      if (ok) C[(long)grow * 128 + wc * 64 + ct * 16 + m16] = f2bf_rne(c);
      ps = fmaf(c, avs_r[ct], ps);
      pd = fmaf(c, avd_r[ct], pd);
    }
#pragma unroll
    for (int d = 1; d < 16; d <<= 1) {
      ps += __shfl_xor(ps, d, 64);
      pd += __shfl_xor(pd, d, 64);
    }
    psA[reg] = ps;
    pdA[reg] = pd;
  }
  // combine col-halves: Bls is dead after final barrier -> alias scratch there
  float* redS = (float*)&Bls[0][0][0];   // [32]
  float* redD = redS + 32;               // [32]
  if (wc == 1 && m16 == 0) {
#pragma unroll
    for (int reg = 0; reg < 4; reg++) {
      int rloc = wr * 16 + q * 4 + reg;
      redS[rloc] = psA[reg];
      redD[rloc] = pdA[reg];
    }
  }
  __syncthreads();
  if (wc == 0 && m16 == 0) {
#pragma unroll
    for (int reg = 0; reg < 4; reg++) {
      int rloc = wr * 16 + q * 4 + reg;
      int grow = row0 + rloc;
      if (grow < M) {
        aS[grow] = psA[reg] + redS[rloc];
        aD[grow] = pdA[reg] + redD[rloc];
      }
    }
  }
}

// ---------------- softmax attention + aggregation: one WAVE per dst ----------------
// Half-wave owns one edge (32 lanes x uint2 = 256B row); 4-deep unroll =>
// 8 edges / 4 independent gathers in flight per lane. Inactive slots (w=0)
// gather node 0's row -> L1-hot, ~free.

__global__ __launch_bounds__(256) void aggregate_kernel(const int* __restrict__ rowptr,
                                                        const int* __restrict__ colA,
                                                        const float* __restrict__ aS,
                                                        const float* __restrict__ aD,
                                                        const unsigned short* __restrict__ Hb,
                                                        const float* __restrict__ bias,
                                                        float* __restrict__ out,
                                                        int apply_gelu) {
  const int lane = threadIdx.x & 63;
  const int dst = blockIdx.x * 4 + (threadIdx.x >> 6);
  if (dst >= NN) return;
  const int start = rowptr[dst];
  const int end = rowptr[dst + 1];
  const int deg = end - start;
  const float ad = aD[dst];
  const int half = lane >> 5;
  const int fl = lane & 31;

  float a0 = 0.f, a1 = 0.f, a2 = 0.f, a3 = 0.f;

  if (deg <= 64) {
    int src = 0;
    float e = -__builtin_inff();
    if (lane < deg) {
      src = colA[start + lane];
      float v = aS[src] + ad;
      e = (v > 0.f) ? v : 0.2f * v;
    }
    float mx = e;
#pragma unroll
    for (int d = 1; d < 64; d <<= 1) mx = fmaxf(mx, __shfl_xor(mx, d, 64));
    float ew = (lane < deg) ? expf(e - mx) : 0.f;
    float ss = ew;
#pragma unroll
    for (int d = 1; d < 64; d <<= 1) ss += __shfl_xor(ss, d, 64);
    float wgt = ew * (1.f / ss);
    for (int j = 0; j < deg; j += 8) {
      int sj[4];
      float wj[4];
#pragma unroll
      for (int i = 0; i < 4; i++) {
        int idx = j + 2 * i + half;
        sj[i] = __shfl(src, idx & 63, 64);
        float ww = __shfl(wgt, idx & 63, 64);
        wj[i] = (idx < deg) ? ww : 0.f;
      }
      uint2 u[4];
#pragma unroll
      for (int i = 0; i < 4; i++) u[i] = *(const uint2*)&Hb[(long)sj[i] * DH + fl * 4];
#pragma unroll
      for (int i = 0; i < 4; i++) {
        a0 = fmaf(wj[i], bf_lo(u[i].x), a0);
        a1 = fmaf(wj[i], bf_hi(u[i].x), a1);
        a2 = fmaf(wj[i], bf_lo(u[i].y), a2);
        a3 = fmaf(wj[i], bf_hi(u[i].y), a3);
      }
    }
  } else {
    float m = -__builtin_inff(), ssum = 0.f;
    for (int c0 = start; c0 < end; c0 += 64) {
      int i = c0 + lane;
      float e = -__builtin_inff();
      if (i < end) {
        int s = colA[i];
        float v = aS[s] + ad;
        e = (v > 0.f) ? v : 0.2f * v;
      }
      float cm = e;
#pragma unroll
      for (int d = 1; d < 64; d <<= 1) cm = fmaxf(cm, __shfl_xor(cm, d, 64));
      float ce = (i < end) ? expf(e - cm) : 0.f;
      float cs = ce;
#pragma unroll
      for (int d = 1; d < 64; d <<= 1) cs += __shfl_xor(cs, d, 64);
      float nm = fmaxf(m, cm);
      ssum = ssum * expf(m - nm) + cs * expf(cm - nm);
      m = nm;
    }
    float inv = 1.f / ssum;
    for (int c0 = start; c0 < end; c0 += 64) {
      int i = c0 + lane;
      int src = 0;
      float wgt = 0.f;
      if (i < end) {
        src = colA[i];
        float v = aS[src] + ad;
        float e = (v > 0.f) ? v : 0.2f * v;
        wgt = expf(e - m) * inv;
      }
      int lim = min(64, end - c0);
      for (int j = 0; j < lim; j += 4) {
        int j0 = j + half;
        int j1 = j + 2 + half;
        int sj0 = __shfl(src, j0 & 63, 64);
        float wj0 = __shfl(wgt, j0 & 63, 64);
        if (j0 >= lim) wj0 = 0.f;
        int sj1 = __shfl(src, j1 & 63, 64);
        float wj1 = __shfl(wgt, j1 & 63, 64);
        if (j1 >= lim) wj1 = 0.f;
        uint2 u0 = *(const uint2*)&Hb[(long)sj0 * DH + fl * 4];
        uint2 u1 = *(const uint2*)&Hb[(long)sj1 * DH + fl * 4];
        a0 = fmaf(wj0, bf_lo(u0.x), a0);
        a1 = fmaf(wj0, bf_hi(u0.x), a1);
        a2 = fmaf(wj0, bf_lo(u0.y), a2);
        a3 = fmaf(wj0, bf_hi(u0.y), a3);
        a0 = fmaf(wj1, bf_lo(u1.x), a0);
        a1 = fmaf(wj1, bf_hi(u1.x), a1);
        a2 = fmaf(wj1, bf_lo(u1.y), a2);
        a3 = fmaf(wj1, bf_hi(u1.y), a3);
      }
    }
  }

  a0 += __shfl_xor(a0, 32, 64);
  a1 += __shfl_xor(a1, 32, 64);
  a2 += __shfl_xor(a2, 32, 64);
  a3 += __shfl_xor(a3, 32, 64);

  if (half == 0) {
    float4 b = *(const float4*)&bias[fl * 4];
    float r0 = a0 + b.x;
    float r1 = a1 + b.y;
    float r2 = a2 + b.z;
    float r3 = a3 + b.w;
    if (apply_gelu) {
      r0 = gelu_exact(r0); r1 = gelu_exact(r1);
      r2 = gelu_exact(r2); r3 = gelu_exact(r3);
    }
    *(float4*)&out[(long)dst * DH + fl * 4] = make_float4(r0, r1, r2, r3);
  }
}

// ---------------- masked per-graph mean pooling (batch is sorted) ----------------

__global__ __launch_bounds__(128) void pool_kernel(const float* __restrict__ H,
                                                   const int* __restrict__ batch,
                                                   const int* __restrict__ pos,
                                                   float* __restrict__ sums,
                                                   float* __restrict__ cnt) {
  const int CH = 64;
  int n0 = blockIdx.x * CH;
  int n1 = min(n0 + CH, NN);
  int f = threadIdx.x;
  float acc = 0.f, c = 0.f;
  int g = batch[n0];
  for (int n = n0; n < n1; n++) {
    int gn = batch[n];
    if (gn != g) {
      atomicAdd(&sums[g * DH + f], acc);
      if (f == 0) atomicAdd(&cnt[g], c);
      acc = 0.f; c = 0.f; g = gn;
    }
    if (pos[n]) {
      acc += H[(long)n * DH + f];
      c += 1.f;
    }
  }
  atomicAdd(&sums[g * DH + f], acc);
  if (f == 0) atomicAdd(&cnt[g], c);
}

// ---------------- head ----------------

__global__ __launch_bounds__(128) void head_kernel(const float* __restrict__ sums,
                                                   const float* __restrict__ cnt,
                                                   const float* __restrict__ Wfc,
                                                   const float* __restrict__ bfc,
                                                   float* __restrict__ out) {
  int g = blockIdx.x;
  int f = threadIdx.x;
  float c = fmaxf(cnt[g], 1.f);
  float logit = sums[g * DH + f] / c;
  out[NG + g * DH + f] = logit;
  float gl = gelu_exact(logit) * Wfc[f];
  __shared__ float red[2];
#pragma unroll
  for (int d = 1; d < 64; d <<= 1) gl += __shfl_xor(gl, d, 64);
  int lane = f & 63, w = f >> 6;
  if (lane == 0) red[w] = gl;
  __syncthreads();
  if (f == 0) out[g] = red[0] + red[1] + bfc[0];
}

// ---------------- launch ----------------

extern "C" void kernel_launch(void* const* d_in, const int* in_sizes, int n_in,
                              void* d_out, int out_size, void* d_ws, size_t ws_size,
                              hipStream_t stream) {
  const float* x   = (const float*)d_in[0];
  const int* ei    = (const int*)d_in[1];
  const int* batch = (const int*)d_in[2];
  const int* pos   = (const int*)d_in[3];
  const float* W1  = (const float*)d_in[5];
  const float* as1 = (const float*)d_in[6];
  const float* ad1 = (const float*)d_in[7];
  const float* b1  = (const float*)d_in[8];
  const float* W2  = (const float*)d_in[9];
  const float* as2 = (const float*)d_in[10];
  const float* ad2 = (const float*)d_in[11];
  const float* b2  = (const float*)d_in[12];
  const float* Wfc = (const float*)d_in[13];
  const float* bfc = (const float*)d_in[14];
  float* out = (float*)d_out;

  const int KP1 = 320;
  const int KP2 = 128;
  const int NB_SCAN = (NN + 1023) / 1024;  // 49
  const int BPR = 416;                      // blocks per dst-range (x8 ranges)

  char* ws = (char*)d_ws;
  size_t off = 0;
  auto nxt = [&](size_t b) -> void* {
    size_t p = off;
    off += (b + 255) & ~(size_t)255;
    return (void*)(ws + p);
  };
  int* rowptr = (int*)nxt((NN + 1) * sizeof(int));
  int* cursor = (int*)nxt(NN * sizeof(int));
  int* colA   = (int*)nxt((size_t)(EE + NN) * sizeof(int));
  int* bsum   = (int*)nxt((NB_SCAN + 1) * sizeof(int));
  int* boff   = (int*)nxt((NB_SCAN + 1) * sizeof(int));
  float* aS   = (float*)nxt((size_t)2 * NN * sizeof(float));
  float* aD   = aS + NN;
  unsigned short* bufAb = (unsigned short*)nxt((size_t)NN * DH * sizeof(short));
  float* bufB = (float*)nxt((size_t)NN * DH * sizeof(float));
  float* sums = (float*)nxt((size_t)(NG * DH + NG) * sizeof(float));
  float* cnt  = sums + NG * DH;
  unsigned short* Bt1h = (unsigned short*)nxt((size_t)128 * KP1 * sizeof(short));
  unsigned short* Bt1l = (unsigned short*)nxt((size_t)128 * KP1 * sizeof(short));
  unsigned short* Bt2h = (unsigned short*)nxt((size_t)128 * KP2 * sizeof(short));
  unsigned short* Bt2l = (unsigned short*)nxt((size_t)128 * KP2 * sizeof(short));

  hipMemsetAsync(cursor, 0, NN * sizeof(int), stream);
  hipMemsetAsync(sums, 0, (NG * DH + NG) * sizeof(float), stream);

  convert_bt_kernel<<<(128 * KP1 + 255) / 256, 256, 0, stream>>>(W1, Bt1h, Bt1l, DIN, KP1);
  convert_bt_kernel<<<(128 * KP2 + 255) / 256, 256, 0, stream>>>(W2, Bt2h, Bt2l, DH, KP2);

  count_part_kernel<<<8 * BPR, 256, 0, stream>>>(ei, cursor, BPR);
  scan_part_kernel<<<NB_SCAN, 1024, 0, stream>>>(cursor, rowptr, bsum);
  scan_sums_kernel<<<1, 64, 0, stream>>>(bsum, boff, NB_SCAN);
  scan_add_kernel<<<(NN + 1 + 255) / 256, 256, 0, stream>>>(rowptr, boff, cursor, NB_SCAN);
  scatter_part_kernel<<<8 * BPR, 256, 0, stream>>>(ei, cursor, colA, BPR);

  const int gblocks = (NN + 31) / 32;
  // layer 1
  gemm_mfma_kernel<<<gblocks, 256, 0, stream>>>(x, Bt1h, Bt1l, bufAb, NN, DIN, KP1,
                                                as1, ad1, aS, aD);
  aggregate_kernel<<<(NN + 3) / 4, 256, 0, stream>>>(rowptr, colA, aS, aD, bufAb, b1, bufB, 1);
  // layer 2
  gemm_mfma_kernel<<<gblocks, 256, 0, stream>>>(bufB, Bt2h, Bt2l, bufAb, NN, DH, KP2,
                                                as2, ad2, aS, aD);
  aggregate_kernel<<<(NN + 3) / 4, 256, 0, stream>>>(rowptr, colA, aS, aD, bufAb, b2, bufB, 0);
  // pooling + head
  pool_kernel<<<(NN + 63) / 64, 128, 0, stream>>>(bufB, batch, pos, sums, cnt);
  head_kernel<<<NG, 128, 0, stream>>>(sums, cnt, Wfc, bfc, out);
}